// Round 1
// baseline (4081.251 us; speedup 1.0000x reference)
//
#include <hip/hip_runtime.h>

#define EPSF 1e-5f
#define THRF 0.2987f

constexpr int N_ = 64, C_ = 128, H_ = 64, W_ = 64;
constexpr int PLANE = H_ * W_;                      // 4096
constexpr size_t TENSOR = (size_t)N_ * C_ * PLANE;  // 33554432
constexpr int NHW = N_ * PLANE;                     // 262144

// ---------------- conv3x3, stride1, pad1, fp32 direct ----------------
// grid = N * (C/8) * (H/4) = 64*16*16 = 16384 blocks, 256 threads.
// Block tile: 4 rows x 64 cols x 8 c_out. Thread: 4 cols x 2 c_out.
__global__ __launch_bounds__(256) void conv3x3_k(const float* __restrict__ in,
                                                 const float* __restrict__ wg,
                                                 float* __restrict__ out) {
    const int b   = blockIdx.x;
    const int h0  = (b & 15) << 2;         // 16 h-groups
    const int co0 = ((b >> 4) & 15) << 3;  // 16 co-groups
    const int n   = b >> 8;

    __shared__ float sIn[6 * 68];  // rows h0-1..h0+4, cols -1..64 (stride 68 for 16B align)
    __shared__ float sW[72];       // 8 co x 9 taps

    const int tid  = threadIdx.x;
    const int row  = tid >> 6;         // 0..3
    const int cog  = (tid >> 4) & 3;   // 0..3 -> co pair
    const int col0 = (tid & 15) << 2;  // 0,4,..,60

    float acc0[4] = {0.f, 0.f, 0.f, 0.f};
    float acc1[4] = {0.f, 0.f, 0.f, 0.f};

    const float* inN = in + (size_t)n * C_ * PLANE;

    for (int ci = 0; ci < C_; ++ci) {
        const float* src = inN + (size_t)ci * PLANE;
        for (int i = tid; i < 396; i += 256) {
            const int r = i / 66, c = i - r * 66;
            const int gh = h0 + r - 1, gw = c - 1;
            float v = 0.f;
            if ((unsigned)gh < 64u && (unsigned)gw < 64u) v = src[gh * 64 + gw];
            sIn[r * 68 + c] = v;
        }
        if (tid < 72) {
            const int co = tid / 9, k = tid - co * 9;
            sW[tid] = wg[((size_t)(co0 + co) * C_ + ci) * 9 + k];
        }
        __syncthreads();

        float iv[3][6];
#pragma unroll
        for (int dr = 0; dr < 3; ++dr)
#pragma unroll
            for (int dc = 0; dc < 6; ++dc)
                iv[dr][dc] = sIn[(row + dr) * 68 + col0 + dc];

        const float* w0 = &sW[(cog * 2 + 0) * 9];
        const float* w1 = &sW[(cog * 2 + 1) * 9];
#pragma unroll
        for (int dr = 0; dr < 3; ++dr)
#pragma unroll
            for (int dc = 0; dc < 3; ++dc) {
                const float wa = w0[dr * 3 + dc];
                const float wb = w1[dr * 3 + dc];
#pragma unroll
                for (int px = 0; px < 4; ++px) {
                    acc0[px] = fmaf(iv[dr][px + dc], wa, acc0[px]);
                    acc1[px] = fmaf(iv[dr][px + dc], wb, acc1[px]);
                }
            }
        __syncthreads();
    }

    const int co_a = co0 + cog * 2;
    float* dst0 = out + (((size_t)n * C_ + co_a) * H_ + (h0 + row)) * W_ + col0;
    float* dst1 = dst0 + (size_t)PLANE;  // co_a + 1
    *(float4*)dst0 = make_float4(acc0[0], acc0[1], acc0[2], acc0[3]);
    *(float4*)dst1 = make_float4(acc1[0], acc1[1], acc1[2], acc1[3]);
}

// ---------------- BN batch statistics (two-stage, deterministic) ----------------
// grid = C*8 = 1024. block (c,s) reduces n in [8s,8s+8) of channel c.
__global__ __launch_bounds__(256) void bn_stats_k(const float* __restrict__ y,
                                                  float* __restrict__ part) {
    const int c = blockIdx.x >> 3, s = blockIdx.x & 7;
    float sum = 0.f, sq = 0.f;
    for (int k = 0; k < 8; ++k) {
        const float4* p = (const float4*)(y + ((size_t)(s * 8 + k) * C_ + c) * PLANE);
        for (int j = threadIdx.x; j < PLANE / 4; j += 256) {
            float4 v = p[j];
            sum += v.x + v.y + v.z + v.w;
            sq  += v.x * v.x + v.y * v.y + v.z * v.z + v.w * v.w;
        }
    }
    __shared__ float rs[256], rq[256];
    rs[threadIdx.x] = sum; rq[threadIdx.x] = sq;
    __syncthreads();
    for (int off = 128; off > 0; off >>= 1) {
        if (threadIdx.x < off) {
            rs[threadIdx.x] += rs[threadIdx.x + off];
            rq[threadIdx.x] += rq[threadIdx.x + off];
        }
        __syncthreads();
    }
    if (threadIdx.x == 0) {
        part[blockIdx.x * 2]     = rs[0];
        part[blockIdx.x * 2 + 1] = rq[0];
    }
}

// 1 block, 128 threads: fold partials -> scale/shift per channel
__global__ void bn_finalize_k(const float* __restrict__ part, const float* __restrict__ gamma,
                              const float* __restrict__ beta, float* __restrict__ st) {
    const int c = threadIdx.x;
    if (c >= C_) return;
    float s = 0.f, q = 0.f;
    for (int k = 0; k < 8; ++k) {
        s += part[(c * 8 + k) * 2];
        q += part[(c * 8 + k) * 2 + 1];
    }
    const float inv  = 1.f / (float)NHW;
    const float mean = s * inv;
    const float var  = q * inv - mean * mean;
    const float sc   = gamma[c] * rsqrtf(var + EPSF);
    st[c]      = sc;
    st[C_ + c] = fmaf(-mean, sc, beta[c]);
}

// ---------------- fused BN-apply + ReLU + per-(n,c) mean mask ----------------
// grid = N*C = 8192 blocks; each block owns one 4096-elem plane.
__global__ __launch_bounds__(256) void bnrelu_mask_k(const float* __restrict__ y1,
                                                     const float* __restrict__ st,
                                                     float* __restrict__ y2) {
    const int p = blockIdx.x;
    const int c = p & (C_ - 1);
    const float sc = st[c], sh = st[C_ + c];
    const float4* src = (const float4*)(y1 + (size_t)p * PLANE);
    float4* dst = (float4*)(y2 + (size_t)p * PLANE);

    float4 v[4];
    float sum = 0.f;
#pragma unroll
    for (int j = 0; j < 4; ++j) {
        float4 t = src[threadIdx.x + 256 * j];
        t.x = fmaxf(fmaf(t.x, sc, sh), 0.f);
        t.y = fmaxf(fmaf(t.y, sc, sh), 0.f);
        t.z = fmaxf(fmaf(t.z, sc, sh), 0.f);
        t.w = fmaxf(fmaf(t.w, sc, sh), 0.f);
        sum += t.x + t.y + t.z + t.w;
        v[j] = t;
    }
    __shared__ float rs[256];
    rs[threadIdx.x] = sum;
    __syncthreads();
    for (int off = 128; off > 0; off >>= 1) {
        if (threadIdx.x < off) rs[threadIdx.x] += rs[threadIdx.x + off];
        __syncthreads();
    }
    const float mean = rs[0] * (1.f / (float)PLANE);
    const float m = (mean >= THRF) ? 1.f : 0.f;
#pragma unroll
    for (int j = 0; j < 4; ++j) {
        float4 t = v[j];
        t.x *= m; t.y *= m; t.z *= m; t.w *= m;
        dst[threadIdx.x + 256 * j] = t;
    }
}

// ---------------- final fused BN + residual + ReLU ----------------
__global__ __launch_bounds__(256) void final_k(const float* __restrict__ y3,
                                               const float* __restrict__ x,
                                               const float* __restrict__ st,
                                               float* __restrict__ out) {
    const size_t total4 = TENSOR / 4;
    for (size_t i = (size_t)blockIdx.x * 256 + threadIdx.x; i < total4;
         i += (size_t)gridDim.x * 256) {
        const int c = (int)((i >> 10) & (C_ - 1));  // 1024 float4 per plane
        const float sc = st[c], sh = st[C_ + c];
        float4 a = ((const float4*)y3)[i];
        float4 b = ((const float4*)x)[i];
        a.x = fmaxf(fmaf(a.x, sc, sh) + b.x, 0.f);
        a.y = fmaxf(fmaf(a.y, sc, sh) + b.y, 0.f);
        a.z = fmaxf(fmaf(a.z, sc, sh) + b.z, 0.f);
        a.w = fmaxf(fmaf(a.w, sc, sh) + b.w, 0.f);
        ((float4*)out)[i] = a;
    }
}

extern "C" void kernel_launch(void* const* d_in, const int* in_sizes, int n_in,
                              void* d_out, int out_size, void* d_ws, size_t ws_size,
                              hipStream_t stream) {
    const float* x  = (const float*)d_in[0];
    const float* w1 = (const float*)d_in[1];
    const float* g1 = (const float*)d_in[2];
    const float* b1 = (const float*)d_in[3];
    const float* w2 = (const float*)d_in[4];
    const float* g2 = (const float*)d_in[5];
    const float* b2 = (const float*)d_in[6];
    float* out  = (float*)d_out;
    float* bufA = (float*)d_ws;           // y1, later y3 (y1 dead after mask pass)
    float* part = bufA + TENSOR;          // 2048 floats
    float* st1  = part + 2048;            // 256 floats (scale|shift)
    float* st2  = st1 + 256;              // 256 floats

    // conv1: x -> bufA
    conv3x3_k<<<16384, 256, 0, stream>>>(x, w1, bufA);
    // BN1 stats
    bn_stats_k<<<1024, 256, 0, stream>>>(bufA, part);
    bn_finalize_k<<<1, 128, 0, stream>>>(part, g1, b1, st1);
    // BN1 apply + relu + channel-mean mask: bufA -> d_out (scratch use)
    bnrelu_mask_k<<<8192, 256, 0, stream>>>(bufA, st1, out);
    // conv2: d_out -> bufA (overwrites y1, which is dead)
    conv3x3_k<<<16384, 256, 0, stream>>>(out, w2, bufA);
    // BN2 stats
    bn_stats_k<<<1024, 256, 0, stream>>>(bufA, part);
    bn_finalize_k<<<1, 128, 0, stream>>>(part, g2, b2, st2);
    // final: relu(bn2(y3) + x) -> d_out
    final_k<<<8192, 256, 0, stream>>>(bufA, x, st2, out);
}

// Round 2
// 538.349 us; speedup vs baseline: 7.5811x; 7.5811x over previous
//
#include <hip/hip_runtime.h>

typedef short short8 __attribute__((ext_vector_type(8)));
typedef float f32x4 __attribute__((ext_vector_type(4)));

#define EPSF 1e-5f
#define THRF 0.2987f

constexpr int N_ = 64, C_ = 128;
constexpr int PLANE = 4096;                         // 64*64
constexpr size_t TENSOR = (size_t)N_ * C_ * PLANE;  // 33554432
constexpr int NHW = N_ * PLANE;                     // 262144

__device__ __forceinline__ unsigned short f2bf(float f) {
    unsigned u = __float_as_uint(f);
    u += 0x7fffu + ((u >> 16) & 1u);  // RNE
    return (unsigned short)(u >> 16);
}

// ---------- weight prep: [co][ci][3][3] fp32 -> [tap][co][ci] bf16 ----------
__global__ __launch_bounds__(256) void prep_w_k(const float* __restrict__ w1,
                                                const float* __restrict__ w2,
                                                unsigned short* __restrict__ Wt1,
                                                unsigned short* __restrict__ Wt2) {
    int idx = blockIdx.x * 256 + threadIdx.x;  // 0..294911
    const int sel = idx >= 147456;
    const float* src = sel ? w2 : w1;
    unsigned short* dst = sel ? Wt2 : Wt1;
    const int r = idx - sel * 147456;
    const int tap = r >> 14;           // r / (128*128)
    const int rem = r & 16383;
    const int co = rem >> 7, ci = rem & 127;
    dst[r] = f2bf(src[(co * 128 + ci) * 9 + tap]);
}

// ---------- NCHW fp32 -> NHWC bf16 transpose (optionally fused BN+ReLU+mask) ----------
// grid = N*H*(C/32) = 64*64*4 = 16384, 256 threads
__global__ __launch_bounds__(256) void to_nhwc_k(const float* __restrict__ src,
                                                 const float* __restrict__ st,
                                                 const float* __restrict__ maskb,
                                                 unsigned short* __restrict__ dst,
                                                 int apply) {
    __shared__ __align__(16) unsigned short tl[64 * 40];  // [w][c-pad40]
    const int b = blockIdx.x;
    const int c0 = (b & 3) * 32;
    const int h  = (b >> 2) & 63;
    const int n  = b >> 8;
    const int t  = threadIdx.x;
    for (int i = t; i < 512; i += 256) {
        const int cl = i >> 4;        // 0..31
        const int c  = c0 + cl;
        const int w4 = (i & 15) * 4;  // 0..60
        float4 v = *(const float4*)&src[(size_t)(n * 128 + c) * 4096 + h * 64 + w4];
        if (apply) {
            const float sc = st[c], sh = st[128 + c];
            const float m  = maskb[n * 128 + c];
            v.x = fmaxf(fmaf(v.x, sc, sh), 0.f) * m;
            v.y = fmaxf(fmaf(v.y, sc, sh), 0.f) * m;
            v.z = fmaxf(fmaf(v.z, sc, sh), 0.f) * m;
            v.w = fmaxf(fmaf(v.w, sc, sh), 0.f) * m;
        }
        tl[(w4 + 0) * 40 + cl] = f2bf(v.x);
        tl[(w4 + 1) * 40 + cl] = f2bf(v.y);
        tl[(w4 + 2) * 40 + cl] = f2bf(v.z);
        tl[(w4 + 3) * 40 + cl] = f2bf(v.w);
    }
    __syncthreads();
    const int w = t >> 2, cs = t & 3;
    short8 v = *(const short8*)&tl[w * 40 + cs * 8];
    *(short8*)&dst[((size_t)n * 4096 + h * 64 + w) * 128 + c0 + cs * 8] = v;
}

// ---------- conv3x3 via MFMA implicit GEMM ----------
// inT: NHWC bf16; Wt: [9][128 co][128 ci] bf16; out: NCHW fp32.
// grid = N * 32 = 2048 blocks, 256 thr (4 waves). Block tile: 128 co x (2 h-rows x 64 w).
// Wave: 64 co x 64 px = 4x4 tiles of 16x16, K=32 per mfma.
__global__ __launch_bounds__(256) void conv_mfma_k(const unsigned short* __restrict__ inT,
                                                   const unsigned short* __restrict__ Wt,
                                                   float* __restrict__ out) {
    __shared__ __align__(16) short sIn[264 * 40];  // [4 rows * 66 cols][32ci pad40]
    __shared__ __align__(16) short sW[128 * 40];   // [128 co][32ci pad40]

    const int b  = blockIdx.x;
    const int h0 = (b & 31) * 2;
    const int n  = b >> 5;
    const int tid  = threadIdx.x;
    const int lane = tid & 63;
    const int wid  = tid >> 6;
    const int co_base = (wid >> 1) * 64;
    const int px_base = (wid & 1) * 64;
    const int lr = lane & 15;  // row(A)/col(B,D) in tile
    const int lg = lane >> 4;  // k-group (A/B), row-group (D)

    f32x4 acc[4][4];
#pragma unroll
    for (int i = 0; i < 4; ++i)
#pragma unroll
        for (int j = 0; j < 4; ++j) acc[i][j] = (f32x4){0.f, 0.f, 0.f, 0.f};

    const size_t inBase = (size_t)n * 4096 * 128;

    for (int cs = 0; cs < 4; ++cs) {
        const int ci0 = cs * 32;
        __syncthreads();  // prev iter's readers done before overwrite
        // stage input tile: 264 spatial x 32 ci (1056 x 16B segs)
        for (int i = tid; i < 1056; i += 256) {
            const int seg = i & 3;
            const int sp  = i >> 2;        // 0..263
            const int r   = sp / 66;
            const int c   = sp - r * 66;
            const int gh  = h0 + r - 1;
            const int gw  = c - 1;
            short8 v = {0, 0, 0, 0, 0, 0, 0, 0};
            if ((unsigned)gh < 64u && (unsigned)gw < 64u)
                v = *(const short8*)&inT[inBase + ((size_t)gh * 64 + gw) * 128 + ci0 + seg * 8];
            *(short8*)&sIn[sp * 40 + seg * 8] = v;
        }
        for (int tap = 0; tap < 9; ++tap) {
            if (tap) __syncthreads();
            // stage weight tile: 128 co x 32 ci
            for (int i = tid; i < 512; i += 256) {
                const int seg = i & 3;
                const int co  = i >> 2;
                *(short8*)&sW[co * 40 + seg * 8] =
                    *(const short8*)&Wt[((size_t)tap * 128 + co) * 128 + ci0 + seg * 8];
            }
            __syncthreads();
            const int dr = tap / 3, dc = tap - dr * 3;
            short8 af[4], bf[4];
#pragma unroll
            for (int i = 0; i < 4; ++i)
                af[i] = *(const short8*)&sW[(co_base + i * 16 + lr) * 40 + lg * 8];
#pragma unroll
            for (int j = 0; j < 4; ++j) {
                const int px = px_base + j * 16 + lr;
                const int r = px >> 6, c = px & 63;
                bf[j] = *(const short8*)&sIn[((r + dr) * 66 + c + dc) * 40 + lg * 8];
            }
#pragma unroll
            for (int i = 0; i < 4; ++i)
#pragma unroll
                for (int j = 0; j < 4; ++j)
                    acc[i][j] = __builtin_amdgcn_mfma_f32_16x16x32_bf16(af[i], bf[j], acc[i][j], 0, 0, 0);
        }
    }
    // write NCHW fp32: D layout col(px)=lane&15, row(co)=lg*4+reg
    const size_t outN = (size_t)n * 128 * 4096;
#pragma unroll
    for (int i = 0; i < 4; ++i) {
        const int cob = co_base + i * 16 + lg * 4;
#pragma unroll
        for (int q = 0; q < 4; ++q) {
            float* op = out + outN + (size_t)(cob + q) * 4096 + h0 * 64 + px_base + lr;
#pragma unroll
            for (int j = 0; j < 4; ++j) op[j * 16] = acc[i][j][q];
        }
    }
}

// ---------- BN batch statistics (two-stage, deterministic), NCHW ----------
__global__ __launch_bounds__(256) void bn_stats_k(const float* __restrict__ y,
                                                  float* __restrict__ part) {
    const int c = blockIdx.x >> 3, s = blockIdx.x & 7;
    float sum = 0.f, sq = 0.f;
    for (int k = 0; k < 8; ++k) {
        const float4* p = (const float4*)(y + ((size_t)(s * 8 + k) * C_ + c) * PLANE);
        for (int j = threadIdx.x; j < PLANE / 4; j += 256) {
            float4 v = p[j];
            sum += v.x + v.y + v.z + v.w;
            sq  += v.x * v.x + v.y * v.y + v.z * v.z + v.w * v.w;
        }
    }
    __shared__ float rs[256], rq[256];
    rs[threadIdx.x] = sum; rq[threadIdx.x] = sq;
    __syncthreads();
    for (int off = 128; off > 0; off >>= 1) {
        if (threadIdx.x < off) {
            rs[threadIdx.x] += rs[threadIdx.x + off];
            rq[threadIdx.x] += rq[threadIdx.x + off];
        }
        __syncthreads();
    }
    if (threadIdx.x == 0) {
        part[blockIdx.x * 2]     = rs[0];
        part[blockIdx.x * 2 + 1] = rq[0];
    }
}

__global__ void bn_finalize_k(const float* __restrict__ part, const float* __restrict__ gamma,
                              const float* __restrict__ beta, float* __restrict__ st) {
    const int c = threadIdx.x;
    if (c >= C_) return;
    float s = 0.f, q = 0.f;
    for (int k = 0; k < 8; ++k) {
        s += part[(c * 8 + k) * 2];
        q += part[(c * 8 + k) * 2 + 1];
    }
    const float inv  = 1.f / (float)NHW;
    const float mean = s * inv;
    const float var  = q * inv - mean * mean;
    const float sc   = gamma[c] * rsqrtf(var + EPSF);
    st[c]       = sc;
    st[C_ + c]  = fmaf(-mean, sc, beta[c]);
}

// ---------- per-(n,c) plane mean of relu(bn(y)) -> mask 0/1 ----------
__global__ __launch_bounds__(256) void mask_means_k(const float* __restrict__ y,
                                                    const float* __restrict__ st,
                                                    float* __restrict__ maskb) {
    const int p = blockIdx.x;  // n*128 + c
    const int c = p & 127;
    const float sc = st[c], sh = st[128 + c];
    const float4* src = (const float4*)(y + (size_t)p * PLANE);
    float s = 0.f;
    for (int j = threadIdx.x; j < 1024; j += 256) {
        float4 v = src[j];
        s += fmaxf(fmaf(v.x, sc, sh), 0.f) + fmaxf(fmaf(v.y, sc, sh), 0.f)
           + fmaxf(fmaf(v.z, sc, sh), 0.f) + fmaxf(fmaf(v.w, sc, sh), 0.f);
    }
    __shared__ float rs[256];
    rs[threadIdx.x] = s;
    __syncthreads();
    for (int o = 128; o > 0; o >>= 1) {
        if (threadIdx.x < o) rs[threadIdx.x] += rs[threadIdx.x + o];
        __syncthreads();
    }
    if (threadIdx.x == 0) maskb[p] = (rs[0] * (1.f / 4096.f) >= THRF) ? 1.f : 0.f;
}

// ---------- final: relu(bn2(y3) + x), NCHW in-place on d_out ----------
__global__ __launch_bounds__(256) void final_k(const float* __restrict__ y3,
                                               const float* __restrict__ x,
                                               const float* __restrict__ st,
                                               float* __restrict__ out) {
    const size_t total4 = TENSOR / 4;
    for (size_t i = (size_t)blockIdx.x * 256 + threadIdx.x; i < total4;
         i += (size_t)gridDim.x * 256) {
        const int c = (int)((i >> 10) & (C_ - 1));
        const float sc = st[c], sh = st[C_ + c];
        float4 a = ((const float4*)y3)[i];
        float4 b = ((const float4*)x)[i];
        a.x = fmaxf(fmaf(a.x, sc, sh) + b.x, 0.f);
        a.y = fmaxf(fmaf(a.y, sc, sh) + b.y, 0.f);
        a.z = fmaxf(fmaf(a.z, sc, sh) + b.z, 0.f);
        a.w = fmaxf(fmaf(a.w, sc, sh) + b.w, 0.f);
        ((float4*)out)[i] = a;
    }
}

extern "C" void kernel_launch(void* const* d_in, const int* in_sizes, int n_in,
                              void* d_out, int out_size, void* d_ws, size_t ws_size,
                              hipStream_t stream) {
    const float* x  = (const float*)d_in[0];
    const float* w1 = (const float*)d_in[1];
    const float* g1 = (const float*)d_in[2];
    const float* b1 = (const float*)d_in[3];
    const float* w2 = (const float*)d_in[4];
    const float* g2 = (const float*)d_in[5];
    const float* b2 = (const float*)d_in[6];
    float* out = (float*)d_out;

    char* wsb = (char*)d_ws;
    unsigned short* io  = (unsigned short*)wsb;                       // 67,108,864 B (NHWC bf16)
    unsigned short* Wt1 = (unsigned short*)(wsb + (size_t)67108864);  // 294,912 B
    unsigned short* Wt2 = Wt1 + 147456;                               // 294,912 B
    float* part  = (float*)(wsb + (size_t)67108864 + 589824);         // 8 KB
    float* st1   = part + 2048;
    float* st2   = st1 + 256;
    float* maskb = st2 + 256;                                         // 8192 floats

    prep_w_k<<<1152, 256, 0, stream>>>(w1, w2, Wt1, Wt2);
    // x -> NHWC bf16
    to_nhwc_k<<<16384, 256, 0, stream>>>(x, st1, maskb, io, 0);
    // conv1: io -> d_out (y1, NCHW fp32)
    conv_mfma_k<<<2048, 256, 0, stream>>>(io, Wt1, out);
    bn_stats_k<<<1024, 256, 0, stream>>>(out, part);
    bn_finalize_k<<<1, 128, 0, stream>>>(part, g1, b1, st1);
    // per-(n,c) means -> mask
    mask_means_k<<<8192, 256, 0, stream>>>(out, st1, maskb);
    // bn1+relu+mask, y1 NCHW -> NHWC bf16 (overwrites io; xT dead)
    to_nhwc_k<<<16384, 256, 0, stream>>>(out, st1, maskb, io, 1);
    // conv2: io -> d_out (y3 overwrites y1, which is dead)
    conv_mfma_k<<<2048, 256, 0, stream>>>(io, Wt2, out);
    bn_stats_k<<<1024, 256, 0, stream>>>(out, part);
    bn_finalize_k<<<1, 128, 0, stream>>>(part, g2, b2, st2);
    // relu(bn2(y3)+x) in-place on d_out
    final_k<<<8192, 256, 0, stream>>>(out, x, st2, out);
}